// Round 1
// baseline (920.848 us; speedup 1.0000x reference)
//
#include <hip/hip_runtime.h>
#include <hip/hip_cooperative_groups.h>
#include <hip/hip_bf16.h>
#include <stdint.h>
#include <stddef.h>

namespace cg = cooperative_groups;

#define RNUM   3
#define NNODES 50000
#define ENUM   1000000
#define BATCH  2048
#define INP    256
#define HID    512
#define OUTC   256
#define BN_EPS 1e-5f
#define NBLK   768
#define NTHR   256
#define BMW    1568   // bitmap words: ceil(50000/32)=1563, padded

typedef __bf16 bf16x8 __attribute__((ext_vector_type(8)));
typedef float  f32x4  __attribute__((ext_vector_type(4)));

__device__ inline unsigned short f2bf(float f) {
    union { float f; unsigned u; } c; c.f = f;
    unsigned u = c.u;
    return (unsigned short)((u + 0x7fffu + ((u >> 16) & 1u)) >> 16);  // RNE
}

__device__ inline uint4 pack8(float4 a, float4 b) {
    uint4 r;
    r.x = (unsigned)f2bf(a.x) | ((unsigned)f2bf(a.y) << 16);
    r.y = (unsigned)f2bf(a.z) | ((unsigned)f2bf(a.w) << 16);
    r.z = (unsigned)f2bf(b.x) | ((unsigned)f2bf(b.y) << 16);
    r.w = (unsigned)f2bf(b.z) | ((unsigned)f2bf(b.w) << 16);
    return r;
}

// =====================================================================
// MEGA KERNEL: entire pipeline in one cooperative launch.
// grid = 768 blocks x 256 threads = exactly 3 blocks/CU on 256 CUs.
// =====================================================================
__global__ __launch_bounds__(NTHR, 3) void k_mega(
    const float* __restrict__ features, const float* __restrict__ W1,
    const float* __restrict__ b1, const float* __restrict__ W2,
    const float* __restrict__ b2, const float* __restrict__ gamma,
    const float* __restrict__ beta, const int* __restrict__ edge_index,
    const int* __restrict__ bn,
    int* inv, int* appear, int* kcount, float* deg,
    float* musum, float* sqsum, unsigned* bitmap,
    unsigned short* W1T, unsigned short* W2T, unsigned short* featB,
    int2* edges, float* xw, float* hbase, float* yw, float* out) {

    cg::grid_group grid = cg::this_grid();
    __shared__ __align__(16) unsigned char smem[16896];
    __shared__ int wsums[4];
    const int tid = threadIdx.x;
    const int bid = blockIdx.x;

    // ---------------- PHASE 0: setup (bitmap, inv scatter, zeros, W^T, featB) ----
    if (bid == 0) {
        for (int i = tid; i < BMW; i += NTHR) bitmap[i] = 0u;
        __syncthreads();
        for (int i = tid; i < BATCH; i += NTHR) {
            int v = bn[i];
            atomicOr(&bitmap[v >> 5], 1u << (v & 31));
        }
    } else if (bid == 1) {
        for (int i = tid; i < BATCH; i += NTHR) inv[bn[i]] = i;
        for (int i = tid; i < RNUM * BATCH; i += NTHR) appear[i] = 0;
        for (int i = tid; i < RNUM * HID; i += NTHR) { musum[i] = 0.f; sqsum[i] = 0.f; }
        if (tid < RNUM) kcount[tid] = 0;
    }
    if (bid < 256) {
        // weight transpose+bf16: 256 tile jobs (z=0: 8x16, z=1: 16x8)
        float* T = (float*)smem;  // [32][33]
        int i = bid;
        int z = i >> 7; i &= 127;
        const float* W = z ? W2 : W1;
        unsigned short* WT = z ? W2T : W1T;
        int K = z ? HID : INP;
        int N = z ? OUTC : HID;
        int kt, nt;
        if (z == 0) { nt = i & 15; kt = i >> 4; } else { nt = i & 7; kt = i >> 3; }
        int tx = tid & 31, ty = tid >> 5;
#pragma unroll
        for (int j = 0; j < 4; ++j)
            T[(ty + j * 8) * 33 + tx] = W[(size_t)(kt * 32 + ty + j * 8) * N + nt * 32 + tx];
        __syncthreads();
#pragma unroll
        for (int j = 0; j < 4; ++j)
            WT[(size_t)(nt * 32 + ty + j * 8) * K + kt * 32 + tx] = f2bf(T[tx * 33 + ty + j * 8]);
    } else if (bid < 640) {
        // featB gather+convert: 384 blocks x 16 rows of [RNUM*BATCH][INP]
        int i = bid - 256;
        int row = i * 16 + (tid >> 4);         // flattened z*BATCH + m
        int c0 = (tid & 15) * 16;
        int z = row >> 11, m = row & 2047;
        const float* srow = features + ((size_t)z * NNODES + bn[m]) * INP;
        unsigned short* drow = featB + (size_t)row * INP;
        float4 f0 = *(const float4*)(srow + c0);
        float4 f1 = *(const float4*)(srow + c0 + 4);
        float4 f2 = *(const float4*)(srow + c0 + 8);
        float4 f3 = *(const float4*)(srow + c0 + 12);
        *(uint4*)(drow + c0)     = pack8(f0, f1);
        *(uint4*)(drow + c0 + 8) = pack8(f2, f3);
    }
    grid.sync();

    // ---------------- PHASE 1: edge mask + compact (bitmap in LDS) --------------
    {
        unsigned* bmL = (unsigned*)smem;
        for (int i = tid; i < BMW; i += NTHR) bmL[i] = bitmap[i];
        __syncthreads();
        const int gsz = NBLK * NTHR;
        const int g0 = bid * NTHR + tid;
        for (int z = 0; z < RNUM; ++z) {
            const int4* s4 = (const int4*)(edge_index + (size_t)z * 2 * ENUM);
            const int4* d4 = (const int4*)(edge_index + (size_t)z * 2 * ENUM + ENUM);
            int2* ed = edges + (size_t)z * ENUM;
            int* app = appear + z * BATCH;
            for (int i = g0; i < ENUM / 4; i += gsz) {
                int4 S = s4[i], D = d4[i];
                int ss[4] = {S.x, S.y, S.z, S.w};
                int dd[4] = {D.x, D.y, D.z, D.w};
#pragma unroll
                for (int u = 0; u < 4; ++u) {
                    int s = ss[u], d = dd[u];
                    unsigned ks = (bmL[s >> 5] >> (s & 31)) & 1u;
                    unsigned kd = (bmL[d >> 5] >> (d & 31)) & 1u;
                    if (ks & kd) {
                        int ps = inv[s], pd = inv[d];
                        int idx = atomicAdd(&kcount[z], 1);
                        ed[idx] = make_int2(ps, pd);
                        app[ps] = 1;
                        app[pd] = 1;
                    }
                }
            }
        }
    }
    grid.sync();

    // ---------------- PHASE 2: scan(appear) -> rank, remap edges, deg (3 blocks)
    if (bid < RNUM) {
        int z = bid;
        int* rk    = (int*)smem;            // [2048]
        float* dgf = (float*)(smem + 8192); // [2048]
        const int* ap = appear + z * BATCH;
        int b0 = tid * 8;
        int pre[8]; int run = 0;
#pragma unroll
        for (int j = 0; j < 8; ++j) { run += ap[b0 + j]; pre[j] = run; }
        int lane = tid & 63, wv = tid >> 6;
        int sc = run;
        for (int off = 1; off < 64; off <<= 1) {
            int n = __shfl_up(sc, off);
            if (lane >= off) sc += n;
        }
        if (lane == 63) wsums[wv] = sc;
        __syncthreads();
        int base = sc - run;
        for (int w = 0; w < wv; ++w) base += wsums[w];
#pragma unroll
        for (int j = 0; j < 8; ++j) { rk[b0 + j] = base + pre[j] - 1; dgf[b0 + j] = 0.f; }
        __syncthreads();
        int K = kcount[z];
        int2* ed = edges + (size_t)z * ENUM;
        for (int e = tid; e < K; e += NTHR) {
            int2 E = ed[e];
            int s = rk[E.x], d = rk[E.y];
            ed[e] = make_int2(s, d);
            atomicAdd(&dgf[d], 1.0f);
        }
        __syncthreads();
        float* dz = deg + z * BATCH;
        for (int i = tid; i < BATCH; i += NTHR) dz[i] = dgf[i];
    }
    grid.sync();

    // ---------------- PHASE 3: GEMM1 (featB bf16 @ W1T) + epilogue --------------
    {
        __syncthreads();
        unsigned short* As = (unsigned short*)smem;            // [64][40]
        unsigned short* Bs = (unsigned short*)(smem + 5120);   // [64][40]
        int z = bid >> 8;
        int r = bid & 255;
        int n0 = (r & 7) * 64, m0 = (r >> 3) * 64;
        int ar = tid >> 2, aq = tid & 3;
        const unsigned short* aptr = featB + (size_t)(z * BATCH + m0 + ar) * INP + aq * 8;
        const unsigned short* bptr = W1T + (size_t)(n0 + ar) * INP + aq * 8;
        int lane = tid & 63, wave = tid >> 6;
        int wm = (wave & 1) * 32, wn = (wave >> 1) * 32;
        int ml = lane & 15, quad = lane >> 4, q8 = quad * 8;
        f32x4 acc[2][2] = {};
        for (int k0 = 0; k0 < INP; k0 += 32) {
            uint4 av = *(const uint4*)(aptr + k0);
            uint4 bv = *(const uint4*)(bptr + k0);
            *(uint4*)&As[ar * 40 + aq * 8] = av;
            *(uint4*)&Bs[ar * 40 + aq * 8] = bv;
            __syncthreads();
            bf16x8 af[2], bfr[2];
#pragma unroll
            for (int mi = 0; mi < 2; ++mi) af[mi]  = *(const bf16x8*)&As[(wm + mi * 16 + ml) * 40 + q8];
#pragma unroll
            for (int ni = 0; ni < 2; ++ni) bfr[ni] = *(const bf16x8*)&Bs[(wn + ni * 16 + ml) * 40 + q8];
#pragma unroll
            for (int mi = 0; mi < 2; ++mi)
#pragma unroll
                for (int ni = 0; ni < 2; ++ni)
                    acc[mi][ni] = __builtin_amdgcn_mfma_f32_16x16x32_bf16(af[mi], bfr[ni], acc[mi][ni], 0, 0, 0);
            __syncthreads();
        }
        const float* dgz = deg + z * BATCH;
        float* xwz = xw + (size_t)z * BATCH * HID;
        float* hbz = hbase + (size_t)z * BATCH * HID;
#pragma unroll
        for (int mi = 0; mi < 2; ++mi)
#pragma unroll
            for (int rr = 0; rr < 4; ++rr) {
                int row = m0 + wm + mi * 16 + quad * 4 + rr;
                float d2 = 1.0f / (dgz[row] + 1.0f);
#pragma unroll
                for (int ni = 0; ni < 2; ++ni) {
                    int col = n0 + wn + ni * 16 + ml;
                    float c = acc[mi][ni][rr];
                    xwz[(size_t)row * HID + col] = c;
                    hbz[(size_t)row * HID + col] = d2 * c + b1[col];
                }
            }
    }
    grid.sync();

    // ---------------- PHASE 4: edge aggregation into hbase ----------------------
    for (int z = 0; z < RNUM; ++z) {
        int K = kcount[z];
        const int2* ed = edges + (size_t)z * ENUM;
        const float* dgz = deg + z * BATCH;
        const float* sm_ = xw + (size_t)z * BATCH * HID;
        float* dm = hbase + (size_t)z * BATCH * HID;
        for (int e = bid; e < K; e += NBLK) {
            int2 E = ed[e];
            float w = rsqrtf(dgz[E.x] + 1.0f) * rsqrtf(dgz[E.y] + 1.0f);
            const float* srow = sm_ + (size_t)E.x * HID;
            float* drow = dm + (size_t)E.y * HID;
            for (int c = tid; c < HID; c += NTHR)
                atomicAdd(&drow[c], w * srow[c]);
        }
    }
    grid.sync();

    // ---------------- PHASE 5: BN stats (192 blocks) ----------------------------
    if (bid < RNUM * 64) {
        int z = bid >> 6;
        int chunk = bid & 63;
        const float* h = hbase + (size_t)z * BATCH * HID;
        int c0 = tid;
        int r0 = chunk * 32;
        float s1a = 0, s2a = 0, s1b = 0, s2b = 0;
        for (int rr = 0; rr < 32; ++rr) {
            const float* row = h + (size_t)(r0 + rr) * HID;
            float va = row[c0];
            float vb = row[c0 + 256];
            s1a += va; s2a += va * va;
            s1b += vb; s2b += vb * vb;
        }
        atomicAdd(&musum[z * HID + c0], s1a);       atomicAdd(&sqsum[z * HID + c0], s2a);
        atomicAdd(&musum[z * HID + c0 + 256], s1b); atomicAdd(&sqsum[z * HID + c0 + 256], s2b);
    }
    grid.sync();

    // ---------------- PHASE 6: BN-final + GEMM2 (384 blocks) --------------------
    if (bid < 384) {
        unsigned short* As = (unsigned short*)smem;            // [64][40]
        unsigned short* Bs = (unsigned short*)(smem + 5120);   // [64][40]
        float* gL = (float*)(smem + 10240);                    // [512]
        float* sL = (float*)(smem + 12288);                    // [512]
        int z = bid >> 7;
        int r = bid & 127;
        int n0 = (r & 3) * 64, m0 = (r >> 2) * 64;
        for (int c = tid; c < HID; c += NTHR) {
            float mu  = musum[z * HID + c] * (1.0f / BATCH);
            float ex2 = sqsum[z * HID + c] * (1.0f / BATCH);
            float var = ex2 - mu * mu;
            float g = rsqrtf(var + BN_EPS) * gamma[c];
            gL[c] = g;
            sL[c] = beta[c] - mu * g;
        }
        __syncthreads();
        int ar = tid >> 2, aq = tid & 3;
        const float* aptr = hbase + (size_t)z * BATCH * HID + (size_t)(m0 + ar) * HID + aq * 8;
        const unsigned short* bptr = W2T + (size_t)(n0 + ar) * HID + aq * 8;
        int lane = tid & 63, wave = tid >> 6;
        int wm = (wave & 1) * 32, wn = (wave >> 1) * 32;
        int ml = lane & 15, quad = lane >> 4, q8 = quad * 8;
        f32x4 acc[2][2] = {};
        for (int k0 = 0; k0 < HID; k0 += 32) {
            float4 h0 = *(const float4*)(aptr + k0);
            float4 h1 = *(const float4*)(aptr + k0 + 4);
            float4 g0 = *(const float4*)(gL + k0 + aq * 8);
            float4 g1 = *(const float4*)(gL + k0 + aq * 8 + 4);
            float4 s0 = *(const float4*)(sL + k0 + aq * 8);
            float4 s1 = *(const float4*)(sL + k0 + aq * 8 + 4);
            float4 a0 = make_float4(h0.x * g0.x + s0.x, h0.y * g0.y + s0.y,
                                    h0.z * g0.z + s0.z, h0.w * g0.w + s0.w);
            float4 a1 = make_float4(h1.x * g1.x + s1.x, h1.y * g1.y + s1.y,
                                    h1.z * g1.z + s1.z, h1.w * g1.w + s1.w);
            uint4 bv = *(const uint4*)(bptr + k0);
            *(uint4*)&As[ar * 40 + aq * 8] = pack8(a0, a1);
            *(uint4*)&Bs[ar * 40 + aq * 8] = bv;
            __syncthreads();
            bf16x8 af[2], bfr[2];
#pragma unroll
            for (int mi = 0; mi < 2; ++mi) af[mi]  = *(const bf16x8*)&As[(wm + mi * 16 + ml) * 40 + q8];
#pragma unroll
            for (int ni = 0; ni < 2; ++ni) bfr[ni] = *(const bf16x8*)&Bs[(wn + ni * 16 + ml) * 40 + q8];
#pragma unroll
            for (int mi = 0; mi < 2; ++mi)
#pragma unroll
                for (int ni = 0; ni < 2; ++ni)
                    acc[mi][ni] = __builtin_amdgcn_mfma_f32_16x16x32_bf16(af[mi], bfr[ni], acc[mi][ni], 0, 0, 0);
            __syncthreads();
        }
        const float* dgz = deg + z * BATCH;
        float* ywz = yw + (size_t)z * BATCH * OUTC;
        float* oz = out + (size_t)z * BATCH * OUTC;
#pragma unroll
        for (int mi = 0; mi < 2; ++mi)
#pragma unroll
            for (int rr = 0; rr < 4; ++rr) {
                int row = m0 + wm + mi * 16 + quad * 4 + rr;
                float d2 = 1.0f / (dgz[row] + 1.0f);
#pragma unroll
                for (int ni = 0; ni < 2; ++ni) {
                    int col = n0 + wn + ni * 16 + ml;
                    float c = acc[mi][ni][rr];
                    ywz[(size_t)row * OUTC + col] = c;
                    oz[(size_t)row * OUTC + col] = d2 * c + b2[col];
                }
            }
    }
    grid.sync();

    // ---------------- PHASE 7: edge aggregation into out ------------------------
    for (int z = 0; z < RNUM; ++z) {
        int K = kcount[z];
        const int2* ed = edges + (size_t)z * ENUM;
        const float* dgz = deg + z * BATCH;
        const float* sm_ = yw + (size_t)z * BATCH * OUTC;
        float* dm = out + (size_t)z * BATCH * OUTC;
        for (int e = bid; e < K; e += NBLK) {
            int2 E = ed[e];
            float w = rsqrtf(dgz[E.x] + 1.0f) * rsqrtf(dgz[E.y] + 1.0f);
            const float* srow = sm_ + (size_t)E.x * OUTC;
            float* drow = dm + (size_t)E.y * OUTC;
            for (int c = tid; c < OUTC; c += NTHR)
                atomicAdd(&drow[c], w * srow[c]);
        }
    }
}

// =====================================================================
// FALLBACK PATH: original verified 12-kernel pipeline (used only if the
// cooperative launch is rejected by the runtime / graph capture).
// =====================================================================

__global__ __launch_bounds__(256) void k_wt(const float* __restrict__ W1,
                                            const float* __restrict__ W2,
                                            unsigned short* __restrict__ W1T,
                                            unsigned short* __restrict__ W2T) {
    __shared__ float T[32][33];
    int z = blockIdx.z;
    const float* W = z ? W2 : W1;
    unsigned short* WT = z ? W2T : W1T;
    int K = z ? HID : INP;
    int N = z ? OUTC : HID;
    int kt = blockIdx.y, nt = blockIdx.x;
    if (kt * 32 >= K || nt * 32 >= N) return;
    int tx = threadIdx.x & 31, ty = threadIdx.x >> 5;
#pragma unroll
    for (int j = 0; j < 4; ++j)
        T[ty + j * 8][tx] = W[(size_t)(kt * 32 + ty + j * 8) * N + nt * 32 + tx];
    __syncthreads();
#pragma unroll
    for (int j = 0; j < 4; ++j)
        WT[(size_t)(nt * 32 + ty + j * 8) * K + kt * 32 + tx] = f2bf(T[tx][ty + j * 8]);
}

__global__ void k_init(int* __restrict__ inv, int* __restrict__ appear,
                       float* __restrict__ deg, float* __restrict__ musum,
                       float* __restrict__ sqsum, int* __restrict__ kcount) {
    int i = blockIdx.x * blockDim.x + threadIdx.x;
    if (i < NNODES) inv[i] = -1;
    if (i < RNUM * BATCH) { appear[i] = 0; deg[i] = 0.0f; }
    if (i < RNUM * HID)   { musum[i] = 0.0f; sqsum[i] = 0.0f; }
    if (i < RNUM)         kcount[i] = 0;
}

__global__ void k_scatter_inv(const int* __restrict__ bn, int* __restrict__ inv) {
    int i = blockIdx.x * blockDim.x + threadIdx.x;
    if (i < BATCH) inv[bn[i]] = i;
}

__global__ void k_mask(const int* __restrict__ edge_index, const int* __restrict__ inv,
                       int* __restrict__ appear, int2* __restrict__ edges,
                       int* __restrict__ kcount) {
    int z = blockIdx.z;
    const int* src = edge_index + (size_t)z * 2 * ENUM;
    const int* dst = src + ENUM;
    int2* ed = edges + (size_t)z * ENUM;
    int* app = appear + z * BATCH;
    int stride = gridDim.x * blockDim.x;
    for (int e4 = blockIdx.x * blockDim.x + threadIdx.x; e4 < ENUM / 4; e4 += stride) {
        int4 s4 = ((const int4*)src)[e4];
        int4 d4 = ((const int4*)dst)[e4];
        int ss[4] = {s4.x, s4.y, s4.z, s4.w};
        int dd[4] = {d4.x, d4.y, d4.z, d4.w};
#pragma unroll
        for (int i = 0; i < 4; ++i) {
            int ps = inv[ss[i]];
            int pd = inv[dd[i]];
            if (ps >= 0 && pd >= 0) {
                int idx = atomicAdd(kcount + z, 1);
                ed[idx] = make_int2(ps, pd);
                app[ps] = 1;
                app[pd] = 1;
            }
        }
    }
}

__global__ __launch_bounds__(1024) void k_scan2048(const int* __restrict__ appear,
                                                   int* __restrict__ rankArr) {
    __shared__ int buf[2][BATCH];
    int z = blockIdx.x;
    const int* ap = appear + z * BATCH;
    int* rk = rankArr + z * BATCH;
    int t = threadIdx.x;
    buf[0][t] = ap[t];
    buf[0][t + 1024] = ap[t + 1024];
    __syncthreads();
    int cur = 0;
    for (int off = 1; off < BATCH; off <<= 1) {
        int nxt = cur ^ 1;
        int i1 = t, i2 = t + 1024;
        buf[nxt][i1] = buf[cur][i1] + (i1 >= off ? buf[cur][i1 - off] : 0);
        buf[nxt][i2] = buf[cur][i2] + (i2 >= off ? buf[cur][i2 - off] : 0);
        __syncthreads();
        cur = nxt;
    }
    rk[t] = buf[cur][t] - 1;
    rk[t + 1024] = buf[cur][t + 1024] - 1;
}

__global__ void k_deg(int2* __restrict__ edges, const int* __restrict__ rankArr,
                      const int* __restrict__ kcount, float* __restrict__ deg) {
    int z = blockIdx.z;
    int K = kcount[z];
    int2* ed = edges + (size_t)z * ENUM;
    const int* rk = rankArr + z * BATCH;
    float* dg = deg + z * BATCH;
    int stride = gridDim.x * blockDim.x;
    for (int e = blockIdx.x * blockDim.x + threadIdx.x; e < K; e += stride) {
        int2 E = ed[e];
        int s = rk[E.x], d = rk[E.y];
        ed[e] = make_int2(s, d);
        atomicAdd(&dg[d], 1.0f);
    }
}

__global__ __launch_bounds__(256) void k_gemm1(
    const float* __restrict__ features, const int* __restrict__ bn,
    const unsigned short* __restrict__ W1T, const float* __restrict__ b1,
    const float* __restrict__ deg, float* __restrict__ xw, float* __restrict__ hbase) {
    __shared__ __align__(16) unsigned short As[64][40];
    __shared__ __align__(16) unsigned short Bs[64][40];
    int z = blockIdx.z;
    const float* feat = features + (size_t)z * NNODES * INP;
    const float* dgz = deg + z * BATCH;
    float* xwz = xw + (size_t)z * BATCH * HID;
    float* hbz = hbase + (size_t)z * BATCH * HID;
    int m0 = blockIdx.y * 64, n0 = blockIdx.x * 64;
    int t = threadIdx.x;
    int ar = t >> 2, aq = t & 3;
    int grow = bn[m0 + ar];
    const float* aptr = feat + (size_t)grow * INP + aq * 8;
    const unsigned short* bptr = W1T + (size_t)(n0 + ar) * INP + aq * 8;

    int lane = t & 63, wave = t >> 6;
    int wm = (wave & 1) * 32, wn = (wave >> 1) * 32;
    int ml = lane & 15, quad = lane >> 4, q8 = quad * 8;

    f32x4 acc[2][2] = {};
    for (int k0 = 0; k0 < INP; k0 += 32) {
        float4 a0 = *(const float4*)(aptr + k0);
        float4 a1 = *(const float4*)(aptr + k0 + 4);
        uint4 bv = *(const uint4*)(bptr + k0);
        *(uint4*)&As[ar][aq * 8] = pack8(a0, a1);
        *(uint4*)&Bs[ar][aq * 8] = bv;
        __syncthreads();
        bf16x8 af[2], bfr[2];
#pragma unroll
        for (int mi = 0; mi < 2; ++mi) af[mi]  = *(const bf16x8*)&As[wm + mi * 16 + ml][q8];
#pragma unroll
        for (int ni = 0; ni < 2; ++ni) bfr[ni] = *(const bf16x8*)&Bs[wn + ni * 16 + ml][q8];
#pragma unroll
        for (int mi = 0; mi < 2; ++mi)
#pragma unroll
            for (int ni = 0; ni < 2; ++ni)
                acc[mi][ni] = __builtin_amdgcn_mfma_f32_16x16x32_bf16(af[mi], bfr[ni], acc[mi][ni], 0, 0, 0);
        __syncthreads();
    }
#pragma unroll
    for (int mi = 0; mi < 2; ++mi)
#pragma unroll
        for (int r = 0; r < 4; ++r) {
            int row = m0 + wm + mi * 16 + quad * 4 + r;
            float d2 = 1.0f / (dgz[row] + 1.0f);
#pragma unroll
            for (int ni = 0; ni < 2; ++ni) {
                int col = n0 + wn + ni * 16 + ml;
                float c = acc[mi][ni][r];
                xwz[(size_t)row * HID + col] = c;
                hbz[(size_t)row * HID + col] = d2 * c + b1[col];
            }
        }
}

__global__ __launch_bounds__(256) void k_gemm2(
    const float* __restrict__ hbase, const float* __restrict__ rstdg,
    const float* __restrict__ shiftc, const unsigned short* __restrict__ W2T,
    const float* __restrict__ b2, const float* __restrict__ deg,
    float* __restrict__ yw, float* __restrict__ out) {
    __shared__ __align__(16) unsigned short As[64][40];
    __shared__ __align__(16) unsigned short Bs[64][40];
    int z = blockIdx.z;
    const float* hz = hbase + (size_t)z * BATCH * HID;
    const float* gz = rstdg + z * HID;
    const float* sz = shiftc + z * HID;
    const float* dgz = deg + z * BATCH;
    float* ywz = yw + (size_t)z * BATCH * OUTC;
    float* oz = out + (size_t)z * BATCH * OUTC;
    int m0 = blockIdx.y * 64, n0 = blockIdx.x * 64;
    int t = threadIdx.x;
    int ar = t >> 2, aq = t & 3;
    const float* aptr = hz + (size_t)(m0 + ar) * HID + aq * 8;
    const unsigned short* bptr = W2T + (size_t)(n0 + ar) * HID + aq * 8;

    int lane = t & 63, wave = t >> 6;
    int wm = (wave & 1) * 32, wn = (wave >> 1) * 32;
    int ml = lane & 15, quad = lane >> 4, q8 = quad * 8;

    f32x4 acc[2][2] = {};
    for (int k0 = 0; k0 < HID; k0 += 32) {
        float4 h0 = *(const float4*)(aptr + k0);
        float4 h1 = *(const float4*)(aptr + k0 + 4);
        float4 g0 = *(const float4*)(gz + k0 + aq * 8);
        float4 g1 = *(const float4*)(gz + k0 + aq * 8 + 4);
        float4 s0 = *(const float4*)(sz + k0 + aq * 8);
        float4 s1 = *(const float4*)(sz + k0 + aq * 8 + 4);
        float4 a0 = make_float4(h0.x * g0.x + s0.x, h0.y * g0.y + s0.y,
                                h0.z * g0.z + s0.z, h0.w * g0.w + s0.w);
        float4 a1 = make_float4(h1.x * g1.x + s1.x, h1.y * g1.y + s1.y,
                                h1.z * g1.z + s1.z, h1.w * g1.w + s1.w);
        uint4 bv = *(const uint4*)(bptr + k0);
        *(uint4*)&As[ar][aq * 8] = pack8(a0, a1);
        *(uint4*)&Bs[ar][aq * 8] = bv;
        __syncthreads();
        bf16x8 af[2], bfr[2];
#pragma unroll
        for (int mi = 0; mi < 2; ++mi) af[mi]  = *(const bf16x8*)&As[wm + mi * 16 + ml][q8];
#pragma unroll
        for (int ni = 0; ni < 2; ++ni) bfr[ni] = *(const bf16x8*)&Bs[wn + ni * 16 + ml][q8];
#pragma unroll
        for (int mi = 0; mi < 2; ++mi)
#pragma unroll
            for (int ni = 0; ni < 2; ++ni)
                acc[mi][ni] = __builtin_amdgcn_mfma_f32_16x16x32_bf16(af[mi], bfr[ni], acc[mi][ni], 0, 0, 0);
        __syncthreads();
    }
#pragma unroll
    for (int mi = 0; mi < 2; ++mi)
#pragma unroll
        for (int r = 0; r < 4; ++r) {
            int row = m0 + wm + mi * 16 + quad * 4 + r;
            float d2 = 1.0f / (dgz[row] + 1.0f);
#pragma unroll
            for (int ni = 0; ni < 2; ++ni) {
                int col = n0 + wn + ni * 16 + ml;
                float c = acc[mi][ni][r];
                ywz[(size_t)row * OUTC + col] = c;
                oz[(size_t)row * OUTC + col] = d2 * c + b2[col];
            }
        }
}

__global__ void k_agg(const int2* __restrict__ edges, const int* __restrict__ kcount,
                      const float* __restrict__ deg, const float* __restrict__ src_mat,
                      float* __restrict__ dst_mat, int ncol) {
    int z = blockIdx.z;
    int K = kcount[z];
    const int2* ed = edges + (size_t)z * ENUM;
    const float* dgz = deg + z * BATCH;
    const float* sm = src_mat + (size_t)z * BATCH * ncol;
    float* dm = dst_mat + (size_t)z * BATCH * ncol;
    for (int e = blockIdx.x; e < K; e += gridDim.x) {
        int2 E = ed[e];
        float w = rsqrtf(dgz[E.x] + 1.0f) * rsqrtf(dgz[E.y] + 1.0f);
        const float* srow = sm + (size_t)E.x * ncol;
        float* drow = dm + (size_t)E.y * ncol;
        for (int c = threadIdx.x; c < ncol; c += blockDim.x)
            atomicAdd(&drow[c], w * srow[c]);
    }
}

__global__ __launch_bounds__(256) void k_bnstats(const float* __restrict__ hbase,
                                                 float* __restrict__ musum,
                                                 float* __restrict__ sqsum) {
    int z = blockIdx.z;
    const float* h = hbase + (size_t)z * BATCH * HID;
    int c0 = threadIdx.x;
    int r0 = blockIdx.x * 32;
    float s1a = 0, s2a = 0, s1b = 0, s2b = 0;
    for (int rr = 0; rr < 32; ++rr) {
        const float* row = h + (size_t)(r0 + rr) * HID;
        float va = row[c0];
        float vb = row[c0 + 256];
        s1a += va; s2a += va * va;
        s1b += vb; s2b += vb * vb;
    }
    atomicAdd(&musum[z * HID + c0], s1a);       atomicAdd(&sqsum[z * HID + c0], s2a);
    atomicAdd(&musum[z * HID + c0 + 256], s1b); atomicAdd(&sqsum[z * HID + c0 + 256], s2b);
}

__global__ void k_bnfinal(const float* __restrict__ musum, const float* __restrict__ sqsum,
                          const float* __restrict__ gamma, const float* __restrict__ beta,
                          float* __restrict__ rstdg, float* __restrict__ shiftc) {
    int z = blockIdx.x;
    int c = threadIdx.x;
    float mu = musum[z * HID + c] * (1.0f / BATCH);
    float ex2 = sqsum[z * HID + c] * (1.0f / BATCH);
    float var = ex2 - mu * mu;
    float g = rsqrtf(var + BN_EPS) * gamma[c];
    rstdg[z * HID + c] = g;
    shiftc[z * HID + c] = beta[c] - mu * g;
}

// ---------------- launch ----------------
extern "C" void kernel_launch(void* const* d_in, const int* in_sizes, int n_in,
                              void* d_out, int out_size, void* d_ws, size_t ws_size,
                              hipStream_t stream) {
    const float* features    = (const float*)d_in[0];
    const float* W1          = (const float*)d_in[1];
    const float* b1          = (const float*)d_in[2];
    const float* W2          = (const float*)d_in[3];
    const float* b2          = (const float*)d_in[4];
    const float* gamma       = (const float*)d_in[5];
    const float* beta        = (const float*)d_in[6];
    const int*   edge_index  = (const int*)d_in[7];
    const int*   batch_nodes = (const int*)d_in[8];
    float* out = (float*)d_out;

    char* p = (char*)d_ws;
    size_t cur = 0;
    auto alloc = [&](size_t bytes) {
        void* r = p + cur;
        cur = (cur + bytes + 255) & ~(size_t)255;
        return r;
    };
    int*   inv    = (int*)  alloc(NNODES * sizeof(int));
    int*   appear = (int*)  alloc(RNUM * BATCH * sizeof(int));
    int*   rankA  = (int*)  alloc(RNUM * BATCH * sizeof(int));
    int*   kcount = (int*)  alloc(RNUM * sizeof(int));
    float* deg    = (float*)alloc(RNUM * BATCH * sizeof(float));
    float* musum  = (float*)alloc(RNUM * HID * sizeof(float));
    float* sqsum  = (float*)alloc(RNUM * HID * sizeof(float));
    float* rstdg  = (float*)alloc(RNUM * HID * sizeof(float));
    float* shiftc = (float*)alloc(RNUM * HID * sizeof(float));
    unsigned* bitmap = (unsigned*)alloc(BMW * sizeof(unsigned));
    unsigned short* W1T = (unsigned short*)alloc((size_t)HID * INP * sizeof(unsigned short));
    unsigned short* W2T = (unsigned short*)alloc((size_t)OUTC * HID * sizeof(unsigned short));
    unsigned short* featB = (unsigned short*)alloc((size_t)RNUM * BATCH * INP * sizeof(unsigned short));
    int2*  edges  = (int2*) alloc((size_t)RNUM * ENUM * sizeof(int2));
    float* xw     = (float*)alloc((size_t)RNUM * BATCH * HID * sizeof(float));
    float* hbase  = (float*)alloc((size_t)RNUM * BATCH * HID * sizeof(float));
    float* yw     = (float*)alloc((size_t)RNUM * BATCH * OUTC * sizeof(float));
    (void)ws_size; (void)in_sizes; (void)n_in; (void)out_size;

    void* kargs[] = {
        (void*)&features, (void*)&W1, (void*)&b1, (void*)&W2, (void*)&b2,
        (void*)&gamma, (void*)&beta, (void*)&edge_index, (void*)&batch_nodes,
        (void*)&inv, (void*)&appear, (void*)&kcount, (void*)&deg,
        (void*)&musum, (void*)&sqsum, (void*)&bitmap,
        (void*)&W1T, (void*)&W2T, (void*)&featB,
        (void*)&edges, (void*)&xw, (void*)&hbase, (void*)&yw, (void*)&out};

    hipError_t err = hipLaunchCooperativeKernel((const void*)k_mega, dim3(NBLK),
                                                dim3(NTHR), kargs, 0, stream);
    if (err != hipSuccess) {
        // Fallback: original verified 12-kernel pipeline.
        k_wt<<<dim3(16, 16, 2), 256, 0, stream>>>(W1, W2, W1T, W2T);
        k_init<<<(NNODES + 255) / 256, 256, 0, stream>>>(inv, appear, deg, musum, sqsum, kcount);
        k_scatter_inv<<<BATCH / 256, 256, 0, stream>>>(batch_nodes, inv);

        k_mask<<<dim3(512, 1, RNUM), 256, 0, stream>>>(edge_index, inv, appear, edges, kcount);
        k_scan2048<<<RNUM, 1024, 0, stream>>>(appear, rankA);
        k_deg<<<dim3(64, 1, RNUM), 256, 0, stream>>>(edges, rankA, kcount, deg);

        k_gemm1<<<dim3(HID / 64, BATCH / 64, RNUM), 256, 0, stream>>>(
            features, batch_nodes, W1T, b1, deg, xw, hbase);
        k_agg<<<dim3(256, 1, RNUM), 256, 0, stream>>>(edges, kcount, deg, xw, hbase, HID);

        k_bnstats<<<dim3(64, 1, RNUM), 256, 0, stream>>>(hbase, musum, sqsum);
        k_bnfinal<<<RNUM, HID, 0, stream>>>(musum, sqsum, gamma, beta, rstdg, shiftc);

        k_gemm2<<<dim3(OUTC / 64, BATCH / 64, RNUM), 256, 0, stream>>>(
            hbase, rstdg, shiftc, W2T, b2, deg, yw, out);
        k_agg<<<dim3(256, 1, RNUM), 256, 0, stream>>>(edges, kcount, deg, yw, out, OUTC);
    }
}

// Round 2
// 759.916 us; speedup vs baseline: 1.2118x; 1.2118x over previous
//
#include <hip/hip_runtime.h>
#include <hip/hip_bf16.h>
#include <stdint.h>
#include <stddef.h>

#define RNUM   3
#define NNODES 50000
#define ENUM   1000000
#define BATCH  2048
#define INP    256
#define HID    512
#define OUTC   256
#define BN_EPS 1e-5f
#define NBLK   768
#define NTHR   256
#define BMW    1568   // bitmap words: ceil(50000/32)=1563, padded
#define NBAR   7      // number of grid barriers in k_mega
#define BARSTRIDE 32  // unsigned words between barrier counters (128 B)

typedef __bf16 bf16x8 __attribute__((ext_vector_type(8)));
typedef float  f32x4  __attribute__((ext_vector_type(4)));

__device__ inline unsigned short f2bf(float f) {
    union { float f; unsigned u; } c; c.f = f;
    unsigned u = c.u;
    return (unsigned short)((u + 0x7fffu + ((u >> 16) & 1u)) >> 16);  // RNE
}

__device__ inline uint4 pack8(float4 a, float4 b) {
    uint4 r;
    r.x = (unsigned)f2bf(a.x) | ((unsigned)f2bf(a.y) << 16);
    r.y = (unsigned)f2bf(a.z) | ((unsigned)f2bf(a.w) << 16);
    r.z = (unsigned)f2bf(b.x) | ((unsigned)f2bf(b.y) << 16);
    r.w = (unsigned)f2bf(b.z) | ((unsigned)f2bf(b.w) << 16);
    return r;
}

// Hand-rolled grid barrier: one counter per barrier ordinal (no reset, no ABA).
// Counters live in our HBM workspace, zeroed by hipMemsetAsync before launch.
// Relaxed agent-scope spin + s_sleep backoff; one release fence (flush my
// writes to the coherence point) before arrival, one acquire fence (drop
// stale XCD-L2 lines) after the barrier opens.
__device__ __forceinline__ void gbar(unsigned* syncbuf, int ord) {
    __syncthreads();
    if (threadIdx.x == 0) {
        unsigned* c = syncbuf + ord * BARSTRIDE;
        __builtin_amdgcn_fence(__ATOMIC_RELEASE, "agent");
        __hip_atomic_fetch_add(c, 1u, __ATOMIC_RELAXED, __HIP_MEMORY_SCOPE_AGENT);
        while (__hip_atomic_load(c, __ATOMIC_RELAXED, __HIP_MEMORY_SCOPE_AGENT) < (unsigned)NBLK) {
            __builtin_amdgcn_s_sleep(2);
        }
        __builtin_amdgcn_fence(__ATOMIC_ACQUIRE, "agent");
    }
    __syncthreads();
}

// =====================================================================
// MEGA KERNEL: entire pipeline in one cooperative launch.
// grid = 768 blocks x 256 threads = exactly 3 blocks/CU on 256 CUs.
// =====================================================================
__global__ __launch_bounds__(NTHR, 3) void k_mega(
    const float* __restrict__ features, const float* __restrict__ W1,
    const float* __restrict__ b1, const float* __restrict__ W2,
    const float* __restrict__ b2, const float* __restrict__ gamma,
    const float* __restrict__ beta, const int* __restrict__ edge_index,
    const int* __restrict__ bn,
    int* inv, int* appear, int* kcount, float* deg,
    float* musum, float* sqsum, unsigned* bitmap,
    unsigned short* W1T, unsigned short* W2T, unsigned short* featB,
    int2* edges, float* xw, float* hbase, float* yw, float* out,
    unsigned* syncbuf) {

    __shared__ __align__(16) unsigned char smem[16896];
    __shared__ int wsums[4];
    const int tid = threadIdx.x;
    const int bid = blockIdx.x;

    // ---------------- PHASE 0: setup (bitmap, inv scatter, zeros, W^T, featB) ----
    if (bid == 0) {
        for (int i = tid; i < BMW; i += NTHR) bitmap[i] = 0u;
        __syncthreads();
        for (int i = tid; i < BATCH; i += NTHR) {
            int v = bn[i];
            atomicOr(&bitmap[v >> 5], 1u << (v & 31));
        }
    } else if (bid == 1) {
        for (int i = tid; i < BATCH; i += NTHR) inv[bn[i]] = i;
        for (int i = tid; i < RNUM * BATCH; i += NTHR) appear[i] = 0;
        for (int i = tid; i < RNUM * HID; i += NTHR) { musum[i] = 0.f; sqsum[i] = 0.f; }
        if (tid < RNUM) kcount[tid] = 0;
    }
    if (bid < 256) {
        // weight transpose+bf16: 256 tile jobs (z=0: 8x16, z=1: 16x8)
        float* T = (float*)smem;  // [32][33]
        int i = bid;
        int z = i >> 7; i &= 127;
        const float* W = z ? W2 : W1;
        unsigned short* WT = z ? W2T : W1T;
        int K = z ? HID : INP;
        int N = z ? OUTC : HID;
        int kt, nt;
        if (z == 0) { nt = i & 15; kt = i >> 4; } else { nt = i & 7; kt = i >> 3; }
        int tx = tid & 31, ty = tid >> 5;
#pragma unroll
        for (int j = 0; j < 4; ++j)
            T[(ty + j * 8) * 33 + tx] = W[(size_t)(kt * 32 + ty + j * 8) * N + nt * 32 + tx];
        __syncthreads();
#pragma unroll
        for (int j = 0; j < 4; ++j)
            WT[(size_t)(nt * 32 + ty + j * 8) * K + kt * 32 + tx] = f2bf(T[tx * 33 + ty + j * 8]);
    } else if (bid < 640) {
        // featB gather+convert: 384 blocks x 16 rows of [RNUM*BATCH][INP]
        int i = bid - 256;
        int row = i * 16 + (tid >> 4);         // flattened z*BATCH + m
        int c0 = (tid & 15) * 16;
        int z = row >> 11, m = row & 2047;
        const float* srow = features + ((size_t)z * NNODES + bn[m]) * INP;
        unsigned short* drow = featB + (size_t)row * INP;
        float4 f0 = *(const float4*)(srow + c0);
        float4 f1 = *(const float4*)(srow + c0 + 4);
        float4 f2 = *(const float4*)(srow + c0 + 8);
        float4 f3 = *(const float4*)(srow + c0 + 12);
        *(uint4*)(drow + c0)     = pack8(f0, f1);
        *(uint4*)(drow + c0 + 8) = pack8(f2, f3);
    }
    gbar(syncbuf, 0);

    // ---------------- PHASE 1: edge mask + compact (bitmap in LDS) --------------
    {
        unsigned* bmL = (unsigned*)smem;
        for (int i = tid; i < BMW; i += NTHR) bmL[i] = bitmap[i];
        __syncthreads();
        const int gsz = NBLK * NTHR;
        const int g0 = bid * NTHR + tid;
        for (int z = 0; z < RNUM; ++z) {
            const int4* s4 = (const int4*)(edge_index + (size_t)z * 2 * ENUM);
            const int4* d4 = (const int4*)(edge_index + (size_t)z * 2 * ENUM + ENUM);
            int2* ed = edges + (size_t)z * ENUM;
            int* app = appear + z * BATCH;
            for (int i = g0; i < ENUM / 4; i += gsz) {
                int4 S = s4[i], D = d4[i];
                int ss[4] = {S.x, S.y, S.z, S.w};
                int dd[4] = {D.x, D.y, D.z, D.w};
#pragma unroll
                for (int u = 0; u < 4; ++u) {
                    int s = ss[u], d = dd[u];
                    unsigned ks = (bmL[s >> 5] >> (s & 31)) & 1u;
                    unsigned kd = (bmL[d >> 5] >> (d & 31)) & 1u;
                    if (ks & kd) {
                        int ps = inv[s], pd = inv[d];
                        int idx = atomicAdd(&kcount[z], 1);
                        ed[idx] = make_int2(ps, pd);
                        app[ps] = 1;
                        app[pd] = 1;
                    }
                }
            }
        }
    }
    gbar(syncbuf, 1);

    // ---------------- PHASE 2: scan(appear) -> rank, remap edges, deg (3 blocks)
    if (bid < RNUM) {
        int z = bid;
        int* rk    = (int*)smem;            // [2048]
        float* dgf = (float*)(smem + 8192); // [2048]
        const int* ap = appear + z * BATCH;
        int b0 = tid * 8;
        int pre[8]; int run = 0;
#pragma unroll
        for (int j = 0; j < 8; ++j) { run += ap[b0 + j]; pre[j] = run; }
        int lane = tid & 63, wv = tid >> 6;
        int sc = run;
        for (int off = 1; off < 64; off <<= 1) {
            int n = __shfl_up(sc, off);
            if (lane >= off) sc += n;
        }
        if (lane == 63) wsums[wv] = sc;
        __syncthreads();
        int base = sc - run;
        for (int w = 0; w < wv; ++w) base += wsums[w];
#pragma unroll
        for (int j = 0; j < 8; ++j) { rk[b0 + j] = base + pre[j] - 1; dgf[b0 + j] = 0.f; }
        __syncthreads();
        int K = kcount[z];
        int2* ed = edges + (size_t)z * ENUM;
        for (int e = tid; e < K; e += NTHR) {
            int2 E = ed[e];
            int s = rk[E.x], d = rk[E.y];
            ed[e] = make_int2(s, d);
            atomicAdd(&dgf[d], 1.0f);
        }
        __syncthreads();
        float* dz = deg + z * BATCH;
        for (int i = tid; i < BATCH; i += NTHR) dz[i] = dgf[i];
    }
    gbar(syncbuf, 2);

    // ---------------- PHASE 3: GEMM1 (featB bf16 @ W1T) + epilogue --------------
    {
        __syncthreads();
        unsigned short* As = (unsigned short*)smem;            // [64][40]
        unsigned short* Bs = (unsigned short*)(smem + 5120);   // [64][40]
        int z = bid >> 8;
        int r = bid & 255;
        int n0 = (r & 7) * 64, m0 = (r >> 3) * 64;
        int ar = tid >> 2, aq = tid & 3;
        const unsigned short* aptr = featB + (size_t)(z * BATCH + m0 + ar) * INP + aq * 8;
        const unsigned short* bptr = W1T + (size_t)(n0 + ar) * INP + aq * 8;
        int lane = tid & 63, wave = tid >> 6;
        int wm = (wave & 1) * 32, wn = (wave >> 1) * 32;
        int ml = lane & 15, quad = lane >> 4, q8 = quad * 8;
        f32x4 acc[2][2] = {};
        for (int k0 = 0; k0 < INP; k0 += 32) {
            uint4 av = *(const uint4*)(aptr + k0);
            uint4 bv = *(const uint4*)(bptr + k0);
            *(uint4*)&As[ar * 40 + aq * 8] = av;
            *(uint4*)&Bs[ar * 40 + aq * 8] = bv;
            __syncthreads();
            bf16x8 af[2], bfr[2];
#pragma unroll
            for (int mi = 0; mi < 2; ++mi) af[mi]  = *(const bf16x8*)&As[(wm + mi * 16 + ml) * 40 + q8];
#pragma unroll
            for (int ni = 0; ni < 2; ++ni) bfr[ni] = *(const bf16x8*)&Bs[(wn + ni * 16 + ml) * 40 + q8];
#pragma unroll
            for (int mi = 0; mi < 2; ++mi)
#pragma unroll
                for (int ni = 0; ni < 2; ++ni)
                    acc[mi][ni] = __builtin_amdgcn_mfma_f32_16x16x32_bf16(af[mi], bfr[ni], acc[mi][ni], 0, 0, 0);
            __syncthreads();
        }
        const float* dgz = deg + z * BATCH;
        float* xwz = xw + (size_t)z * BATCH * HID;
        float* hbz = hbase + (size_t)z * BATCH * HID;
#pragma unroll
        for (int mi = 0; mi < 2; ++mi)
#pragma unroll
            for (int rr = 0; rr < 4; ++rr) {
                int row = m0 + wm + mi * 16 + quad * 4 + rr;
                float d2 = 1.0f / (dgz[row] + 1.0f);
#pragma unroll
                for (int ni = 0; ni < 2; ++ni) {
                    int col = n0 + wn + ni * 16 + ml;
                    float c = acc[mi][ni][rr];
                    xwz[(size_t)row * HID + col] = c;
                    hbz[(size_t)row * HID + col] = d2 * c + b1[col];
                }
            }
    }
    gbar(syncbuf, 3);

    // ---------------- PHASE 4: edge aggregation into hbase ----------------------
    for (int z = 0; z < RNUM; ++z) {
        int K = kcount[z];
        const int2* ed = edges + (size_t)z * ENUM;
        const float* dgz = deg + z * BATCH;
        const float* sm_ = xw + (size_t)z * BATCH * HID;
        float* dm = hbase + (size_t)z * BATCH * HID;
        for (int e = bid; e < K; e += NBLK) {
            int2 E = ed[e];
            float w = rsqrtf(dgz[E.x] + 1.0f) * rsqrtf(dgz[E.y] + 1.0f);
            const float* srow = sm_ + (size_t)E.x * HID;
            float* drow = dm + (size_t)E.y * HID;
            for (int c = tid; c < HID; c += NTHR)
                atomicAdd(&drow[c], w * srow[c]);
        }
    }
    gbar(syncbuf, 4);

    // ---------------- PHASE 5: BN stats (192 blocks) ----------------------------
    if (bid < RNUM * 64) {
        int z = bid >> 6;
        int chunk = bid & 63;
        const float* h = hbase + (size_t)z * BATCH * HID;
        int c0 = tid;
        int r0 = chunk * 32;
        float s1a = 0, s2a = 0, s1b = 0, s2b = 0;
        for (int rr = 0; rr < 32; ++rr) {
            const float* row = h + (size_t)(r0 + rr) * HID;
            float va = row[c0];
            float vb = row[c0 + 256];
            s1a += va; s2a += va * va;
            s1b += vb; s2b += vb * vb;
        }
        atomicAdd(&musum[z * HID + c0], s1a);       atomicAdd(&sqsum[z * HID + c0], s2a);
        atomicAdd(&musum[z * HID + c0 + 256], s1b); atomicAdd(&sqsum[z * HID + c0 + 256], s2b);
    }
    gbar(syncbuf, 5);

    // ---------------- PHASE 6: BN-final + GEMM2 (384 blocks) --------------------
    if (bid < 384) {
        unsigned short* As = (unsigned short*)smem;            // [64][40]
        unsigned short* Bs = (unsigned short*)(smem + 5120);   // [64][40]
        float* gL = (float*)(smem + 10240);                    // [512]
        float* sL = (float*)(smem + 12288);                    // [512]
        int z = bid >> 7;
        int r = bid & 127;
        int n0 = (r & 3) * 64, m0 = (r >> 2) * 64;
        for (int c = tid; c < HID; c += NTHR) {
            float mu  = musum[z * HID + c] * (1.0f / BATCH);
            float ex2 = sqsum[z * HID + c] * (1.0f / BATCH);
            float var = ex2 - mu * mu;
            float g = rsqrtf(var + BN_EPS) * gamma[c];
            gL[c] = g;
            sL[c] = beta[c] - mu * g;
        }
        __syncthreads();
        int ar = tid >> 2, aq = tid & 3;
        const float* aptr = hbase + (size_t)z * BATCH * HID + (size_t)(m0 + ar) * HID + aq * 8;
        const unsigned short* bptr = W2T + (size_t)(n0 + ar) * HID + aq * 8;
        int lane = tid & 63, wave = tid >> 6;
        int wm = (wave & 1) * 32, wn = (wave >> 1) * 32;
        int ml = lane & 15, quad = lane >> 4, q8 = quad * 8;
        f32x4 acc[2][2] = {};
        for (int k0 = 0; k0 < HID; k0 += 32) {
            float4 h0 = *(const float4*)(aptr + k0);
            float4 h1 = *(const float4*)(aptr + k0 + 4);
            float4 g0 = *(const float4*)(gL + k0 + aq * 8);
            float4 g1 = *(const float4*)(gL + k0 + aq * 8 + 4);
            float4 s0 = *(const float4*)(sL + k0 + aq * 8);
            float4 s1 = *(const float4*)(sL + k0 + aq * 8 + 4);
            float4 a0 = make_float4(h0.x * g0.x + s0.x, h0.y * g0.y + s0.y,
                                    h0.z * g0.z + s0.z, h0.w * g0.w + s0.w);
            float4 a1 = make_float4(h1.x * g1.x + s1.x, h1.y * g1.y + s1.y,
                                    h1.z * g1.z + s1.z, h1.w * g1.w + s1.w);
            uint4 bv = *(const uint4*)(bptr + k0);
            *(uint4*)&As[ar * 40 + aq * 8] = pack8(a0, a1);
            *(uint4*)&Bs[ar * 40 + aq * 8] = bv;
            __syncthreads();
            bf16x8 af[2], bfr[2];
#pragma unroll
            for (int mi = 0; mi < 2; ++mi) af[mi]  = *(const bf16x8*)&As[(wm + mi * 16 + ml) * 40 + q8];
#pragma unroll
            for (int ni = 0; ni < 2; ++ni) bfr[ni] = *(const bf16x8*)&Bs[(wn + ni * 16 + ml) * 40 + q8];
#pragma unroll
            for (int mi = 0; mi < 2; ++mi)
#pragma unroll
                for (int ni = 0; ni < 2; ++ni)
                    acc[mi][ni] = __builtin_amdgcn_mfma_f32_16x16x32_bf16(af[mi], bfr[ni], acc[mi][ni], 0, 0, 0);
            __syncthreads();
        }
        const float* dgz = deg + z * BATCH;
        float* ywz = yw + (size_t)z * BATCH * OUTC;
        float* oz = out + (size_t)z * BATCH * OUTC;
#pragma unroll
        for (int mi = 0; mi < 2; ++mi)
#pragma unroll
            for (int rr = 0; rr < 4; ++rr) {
                int row = m0 + wm + mi * 16 + quad * 4 + rr;
                float d2 = 1.0f / (dgz[row] + 1.0f);
#pragma unroll
                for (int ni = 0; ni < 2; ++ni) {
                    int col = n0 + wn + ni * 16 + ml;
                    float c = acc[mi][ni][rr];
                    ywz[(size_t)row * OUTC + col] = c;
                    oz[(size_t)row * OUTC + col] = d2 * c + b2[col];
                }
            }
    }
    gbar(syncbuf, 6);

    // ---------------- PHASE 7: edge aggregation into out ------------------------
    for (int z = 0; z < RNUM; ++z) {
        int K = kcount[z];
        const int2* ed = edges + (size_t)z * ENUM;
        const float* dgz = deg + z * BATCH;
        const float* sm_ = yw + (size_t)z * BATCH * OUTC;
        float* dm = out + (size_t)z * BATCH * OUTC;
        for (int e = bid; e < K; e += NBLK) {
            int2 E = ed[e];
            float w = rsqrtf(dgz[E.x] + 1.0f) * rsqrtf(dgz[E.y] + 1.0f);
            const float* srow = sm_ + (size_t)E.x * OUTC;
            float* drow = dm + (size_t)E.y * OUTC;
            for (int c = tid; c < OUTC; c += NTHR)
                atomicAdd(&drow[c], w * srow[c]);
        }
    }
}

// =====================================================================
// FALLBACK PATH: original verified 12-kernel pipeline (used only if the
// cooperative launch is rejected by the runtime / graph capture).
// =====================================================================

__global__ __launch_bounds__(256) void k_wt(const float* __restrict__ W1,
                                            const float* __restrict__ W2,
                                            unsigned short* __restrict__ W1T,
                                            unsigned short* __restrict__ W2T) {
    __shared__ float T[32][33];
    int z = blockIdx.z;
    const float* W = z ? W2 : W1;
    unsigned short* WT = z ? W2T : W1T;
    int K = z ? HID : INP;
    int N = z ? OUTC : HID;
    int kt = blockIdx.y, nt = blockIdx.x;
    if (kt * 32 >= K || nt * 32 >= N) return;
    int tx = threadIdx.x & 31, ty = threadIdx.x >> 5;
#pragma unroll
    for (int j = 0; j < 4; ++j)
        T[ty + j * 8][tx] = W[(size_t)(kt * 32 + ty + j * 8) * N + nt * 32 + tx];
    __syncthreads();
#pragma unroll
    for (int j = 0; j < 4; ++j)
        WT[(size_t)(nt * 32 + ty + j * 8) * K + kt * 32 + tx] = f2bf(T[tx][ty + j * 8]);
}

__global__ void k_init(int* __restrict__ inv, int* __restrict__ appear,
                       float* __restrict__ deg, float* __restrict__ musum,
                       float* __restrict__ sqsum, int* __restrict__ kcount) {
    int i = blockIdx.x * blockDim.x + threadIdx.x;
    if (i < NNODES) inv[i] = -1;
    if (i < RNUM * BATCH) { appear[i] = 0; deg[i] = 0.0f; }
    if (i < RNUM * HID)   { musum[i] = 0.0f; sqsum[i] = 0.0f; }
    if (i < RNUM)         kcount[i] = 0;
}

__global__ void k_scatter_inv(const int* __restrict__ bn, int* __restrict__ inv) {
    int i = blockIdx.x * blockDim.x + threadIdx.x;
    if (i < BATCH) inv[bn[i]] = i;
}

__global__ void k_mask(const int* __restrict__ edge_index, const int* __restrict__ inv,
                       int* __restrict__ appear, int2* __restrict__ edges,
                       int* __restrict__ kcount) {
    int z = blockIdx.z;
    const int* src = edge_index + (size_t)z * 2 * ENUM;
    const int* dst = src + ENUM;
    int2* ed = edges + (size_t)z * ENUM;
    int* app = appear + z * BATCH;
    int stride = gridDim.x * blockDim.x;
    for (int e4 = blockIdx.x * blockDim.x + threadIdx.x; e4 < ENUM / 4; e4 += stride) {
        int4 s4 = ((const int4*)src)[e4];
        int4 d4 = ((const int4*)dst)[e4];
        int ss[4] = {s4.x, s4.y, s4.z, s4.w};
        int dd[4] = {d4.x, d4.y, d4.z, d4.w};
#pragma unroll
        for (int i = 0; i < 4; ++i) {
            int ps = inv[ss[i]];
            int pd = inv[dd[i]];
            if (ps >= 0 && pd >= 0) {
                int idx = atomicAdd(kcount + z, 1);
                ed[idx] = make_int2(ps, pd);
                app[ps] = 1;
                app[pd] = 1;
            }
        }
    }
}

__global__ __launch_bounds__(1024) void k_scan2048(const int* __restrict__ appear,
                                                   int* __restrict__ rankArr) {
    __shared__ int buf[2][BATCH];
    int z = blockIdx.x;
    const int* ap = appear + z * BATCH;
    int* rk = rankArr + z * BATCH;
    int t = threadIdx.x;
    buf[0][t] = ap[t];
    buf[0][t + 1024] = ap[t + 1024];
    __syncthreads();
    int cur = 0;
    for (int off = 1; off < BATCH; off <<= 1) {
        int nxt = cur ^ 1;
        int i1 = t, i2 = t + 1024;
        buf[nxt][i1] = buf[cur][i1] + (i1 >= off ? buf[cur][i1 - off] : 0);
        buf[nxt][i2] = buf[cur][i2] + (i2 >= off ? buf[cur][i2 - off] : 0);
        __syncthreads();
        cur = nxt;
    }
    rk[t] = buf[cur][t] - 1;
    rk[t + 1024] = buf[cur][t + 1024] - 1;
}

__global__ void k_deg(int2* __restrict__ edges, const int* __restrict__ rankArr,
                      const int* __restrict__ kcount, float* __restrict__ deg) {
    int z = blockIdx.z;
    int K = kcount[z];
    int2* ed = edges + (size_t)z * ENUM;
    const int* rk = rankArr + z * BATCH;
    float* dg = deg + z * BATCH;
    int stride = gridDim.x * blockDim.x;
    for (int e = blockIdx.x * blockDim.x + threadIdx.x; e < K; e += stride) {
        int2 E = ed[e];
        int s = rk[E.x], d = rk[E.y];
        ed[e] = make_int2(s, d);
        atomicAdd(&dg[d], 1.0f);
    }
}

__global__ __launch_bounds__(256) void k_gemm1(
    const float* __restrict__ features, const int* __restrict__ bn,
    const unsigned short* __restrict__ W1T, const float* __restrict__ b1,
    const float* __restrict__ deg, float* __restrict__ xw, float* __restrict__ hbase) {
    __shared__ __align__(16) unsigned short As[64][40];
    __shared__ __align__(16) unsigned short Bs[64][40];
    int z = blockIdx.z;
    const float* feat = features + (size_t)z * NNODES * INP;
    const float* dgz = deg + z * BATCH;
    float* xwz = xw + (size_t)z * BATCH * HID;
    float* hbz = hbase + (size_t)z * BATCH * HID;
    int m0 = blockIdx.y * 64, n0 = blockIdx.x * 64;
    int t = threadIdx.x;
    int ar = t >> 2, aq = t & 3;
    int grow = bn[m0 + ar];
    const float* aptr = feat + (size_t)grow * INP + aq * 8;
    const unsigned short* bptr = W1T + (size_t)(n0 + ar) * INP + aq * 8;

    int lane = t & 63, wave = t >> 6;
    int wm = (wave & 1) * 32, wn = (wave >> 1) * 32;
    int ml = lane & 15, quad = lane >> 4, q8 = quad * 8;

    f32x4 acc[2][2] = {};
    for (int k0 = 0; k0 < INP; k0 += 32) {
        float4 a0 = *(const float4*)(aptr + k0);
        float4 a1 = *(const float4*)(aptr + k0 + 4);
        uint4 bv = *(const uint4*)(bptr + k0);
        *(uint4*)&As[ar][aq * 8] = pack8(a0, a1);
        *(uint4*)&Bs[ar][aq * 8] = bv;
        __syncthreads();
        bf16x8 af[2], bfr[2];
#pragma unroll
        for (int mi = 0; mi < 2; ++mi) af[mi]  = *(const bf16x8*)&As[wm + mi * 16 + ml][q8];
#pragma unroll
        for (int ni = 0; ni < 2; ++ni) bfr[ni] = *(const bf16x8*)&Bs[wn + ni * 16 + ml][q8];
#pragma unroll
        for (int mi = 0; mi < 2; ++mi)
#pragma unroll
            for (int ni = 0; ni < 2; ++ni)
                acc[mi][ni] = __builtin_amdgcn_mfma_f32_16x16x32_bf16(af[mi], bfr[ni], acc[mi][ni], 0, 0, 0);
        __syncthreads();
    }
#pragma unroll
    for (int mi = 0; mi < 2; ++mi)
#pragma unroll
        for (int r = 0; r < 4; ++r) {
            int row = m0 + wm + mi * 16 + quad * 4 + r;
            float d2 = 1.0f / (dgz[row] + 1.0f);
#pragma unroll
            for (int ni = 0; ni < 2; ++ni) {
                int col = n0 + wn + ni * 16 + ml;
                float c = acc[mi][ni][r];
                xwz[(size_t)row * HID + col] = c;
                hbz[(size_t)row * HID + col] = d2 * c + b1[col];
            }
        }
}

__global__ __launch_bounds__(256) void k_gemm2(
    const float* __restrict__ hbase, const float* __restrict__ rstdg,
    const float* __restrict__ shiftc, const unsigned short* __restrict__ W2T,
    const float* __restrict__ b2, const float* __restrict__ deg,
    float* __restrict__ yw, float* __restrict__ out) {
    __shared__ __align__(16) unsigned short As[64][40];
    __shared__ __align__(16) unsigned short Bs[64][40];
    int z = blockIdx.z;
    const float* hz = hbase + (size_t)z * BATCH * HID;
    const float* gz = rstdg + z * HID;
    const float* sz = shiftc + z * HID;
    const float* dgz = deg + z * BATCH;
    float* ywz = yw + (size_t)z * BATCH * OUTC;
    float* oz = out + (size_t)z * BATCH * OUTC;
    int m0 = blockIdx.y * 64, n0 = blockIdx.x * 64;
    int t = threadIdx.x;
    int ar = t >> 2, aq = t & 3;
    const float* aptr = hz + (size_t)(m0 + ar) * HID + aq * 8;
    const unsigned short* bptr = W2T + (size_t)(n0 + ar) * HID + aq * 8;

    int lane = t & 63, wave = t >> 6;
    int wm = (wave & 1) * 32, wn = (wave >> 1) * 32;
    int ml = lane & 15, quad = lane >> 4, q8 = quad * 8;

    f32x4 acc[2][2] = {};
    for (int k0 = 0; k0 < HID; k0 += 32) {
        float4 h0 = *(const float4*)(aptr + k0);
        float4 h1 = *(const float4*)(aptr + k0 + 4);
        float4 g0 = *(const float4*)(gz + k0 + aq * 8);
        float4 g1 = *(const float4*)(gz + k0 + aq * 8 + 4);
        float4 s0 = *(const float4*)(sz + k0 + aq * 8);
        float4 s1 = *(const float4*)(sz + k0 + aq * 8 + 4);
        float4 a0 = make_float4(h0.x * g0.x + s0.x, h0.y * g0.y + s0.y,
                                h0.z * g0.z + s0.z, h0.w * g0.w + s0.w);
        float4 a1 = make_float4(h1.x * g1.x + s1.x, h1.y * g1.y + s1.y,
                                h1.z * g1.z + s1.z, h1.w * g1.w + s1.w);
        uint4 bv = *(const uint4*)(bptr + k0);
        *(uint4*)&As[ar][aq * 8] = pack8(a0, a1);
        *(uint4*)&Bs[ar][aq * 8] = bv;
        __syncthreads();
        bf16x8 af[2], bfr[2];
#pragma unroll
        for (int mi = 0; mi < 2; ++mi) af[mi]  = *(const bf16x8*)&As[wm + mi * 16 + ml][q8];
#pragma unroll
        for (int ni = 0; ni < 2; ++ni) bfr[ni] = *(const bf16x8*)&Bs[wn + ni * 16 + ml][q8];
#pragma unroll
        for (int mi = 0; mi < 2; ++mi)
#pragma unroll
            for (int ni = 0; ni < 2; ++ni)
                acc[mi][ni] = __builtin_amdgcn_mfma_f32_16x16x32_bf16(af[mi], bfr[ni], acc[mi][ni], 0, 0, 0);
        __syncthreads();
    }
#pragma unroll
    for (int mi = 0; mi < 2; ++mi)
#pragma unroll
        for (int r = 0; r < 4; ++r) {
            int row = m0 + wm + mi * 16 + quad * 4 + r;
            float d2 = 1.0f / (dgz[row] + 1.0f);
#pragma unroll
            for (int ni = 0; ni < 2; ++ni) {
                int col = n0 + wn + ni * 16 + ml;
                float c = acc[mi][ni][r];
                ywz[(size_t)row * OUTC + col] = c;
                oz[(size_t)row * OUTC + col] = d2 * c + b2[col];
            }
        }
}

__global__ void k_agg(const int2* __restrict__ edges, const int* __restrict__ kcount,
                      const float* __restrict__ deg, const float* __restrict__ src_mat,
                      float* __restrict__ dst_mat, int ncol) {
    int z = blockIdx.z;
    int K = kcount[z];
    const int2* ed = edges + (size_t)z * ENUM;
    const float* dgz = deg + z * BATCH;
    const float* sm = src_mat + (size_t)z * BATCH * ncol;
    float* dm = dst_mat + (size_t)z * BATCH * ncol;
    for (int e = blockIdx.x; e < K; e += gridDim.x) {
        int2 E = ed[e];
        float w = rsqrtf(dgz[E.x] + 1.0f) * rsqrtf(dgz[E.y] + 1.0f);
        const float* srow = sm + (size_t)E.x * ncol;
        float* drow = dm + (size_t)E.y * ncol;
        for (int c = threadIdx.x; c < ncol; c += blockDim.x)
            atomicAdd(&drow[c], w * srow[c]);
    }
}

__global__ __launch_bounds__(256) void k_bnstats(const float* __restrict__ hbase,
                                                 float* __restrict__ musum,
                                                 float* __restrict__ sqsum) {
    int z = blockIdx.z;
    const float* h = hbase + (size_t)z * BATCH * HID;
    int c0 = threadIdx.x;
    int r0 = blockIdx.x * 32;
    float s1a = 0, s2a = 0, s1b = 0, s2b = 0;
    for (int rr = 0; rr < 32; ++rr) {
        const float* row = h + (size_t)(r0 + rr) * HID;
        float va = row[c0];
        float vb = row[c0 + 256];
        s1a += va; s2a += va * va;
        s1b += vb; s2b += vb * vb;
    }
    atomicAdd(&musum[z * HID + c0], s1a);       atomicAdd(&sqsum[z * HID + c0], s2a);
    atomicAdd(&musum[z * HID + c0 + 256], s1b); atomicAdd(&sqsum[z * HID + c0 + 256], s2b);
}

__global__ void k_bnfinal(const float* __restrict__ musum, const float* __restrict__ sqsum,
                          const float* __restrict__ gamma, const float* __restrict__ beta,
                          float* __restrict__ rstdg, float* __restrict__ shiftc) {
    int z = blockIdx.x;
    int c = threadIdx.x;
    float mu = musum[z * HID + c] * (1.0f / BATCH);
    float ex2 = sqsum[z * HID + c] * (1.0f / BATCH);
    float var = ex2 - mu * mu;
    float g = rsqrtf(var + BN_EPS) * gamma[c];
    rstdg[z * HID + c] = g;
    shiftc[z * HID + c] = beta[c] - mu * g;
}

// ---------------- launch ----------------
extern "C" void kernel_launch(void* const* d_in, const int* in_sizes, int n_in,
                              void* d_out, int out_size, void* d_ws, size_t ws_size,
                              hipStream_t stream) {
    const float* features    = (const float*)d_in[0];
    const float* W1          = (const float*)d_in[1];
    const float* b1          = (const float*)d_in[2];
    const float* W2          = (const float*)d_in[3];
    const float* b2          = (const float*)d_in[4];
    const float* gamma       = (const float*)d_in[5];
    const float* beta        = (const float*)d_in[6];
    const int*   edge_index  = (const int*)d_in[7];
    const int*   batch_nodes = (const int*)d_in[8];
    float* out = (float*)d_out;

    char* p = (char*)d_ws;
    size_t cur = 0;
    auto alloc = [&](size_t bytes) {
        void* r = p + cur;
        cur = (cur + bytes + 255) & ~(size_t)255;
        return r;
    };
    int*   inv    = (int*)  alloc(NNODES * sizeof(int));
    int*   appear = (int*)  alloc(RNUM * BATCH * sizeof(int));
    int*   rankA  = (int*)  alloc(RNUM * BATCH * sizeof(int));
    int*   kcount = (int*)  alloc(RNUM * sizeof(int));
    float* deg    = (float*)alloc(RNUM * BATCH * sizeof(float));
    float* musum  = (float*)alloc(RNUM * HID * sizeof(float));
    float* sqsum  = (float*)alloc(RNUM * HID * sizeof(float));
    float* rstdg  = (float*)alloc(RNUM * HID * sizeof(float));
    float* shiftc = (float*)alloc(RNUM * HID * sizeof(float));
    unsigned* bitmap = (unsigned*)alloc(BMW * sizeof(unsigned));
    unsigned* syncbuf = (unsigned*)alloc(NBAR * BARSTRIDE * sizeof(unsigned));
    unsigned short* W1T = (unsigned short*)alloc((size_t)HID * INP * sizeof(unsigned short));
    unsigned short* W2T = (unsigned short*)alloc((size_t)OUTC * HID * sizeof(unsigned short));
    unsigned short* featB = (unsigned short*)alloc((size_t)RNUM * BATCH * INP * sizeof(unsigned short));
    int2*  edges  = (int2*) alloc((size_t)RNUM * ENUM * sizeof(int2));
    float* xw     = (float*)alloc((size_t)RNUM * BATCH * HID * sizeof(float));
    float* hbase  = (float*)alloc((size_t)RNUM * BATCH * HID * sizeof(float));
    float* yw     = (float*)alloc((size_t)RNUM * BATCH * OUTC * sizeof(float));
    (void)ws_size; (void)in_sizes; (void)n_in; (void)out_size;

    // zero the grid-barrier counters (captured in the same stream/graph)
    hipMemsetAsync(syncbuf, 0, NBAR * BARSTRIDE * sizeof(unsigned), stream);

    void* kargs[] = {
        (void*)&features, (void*)&W1, (void*)&b1, (void*)&W2, (void*)&b2,
        (void*)&gamma, (void*)&beta, (void*)&edge_index, (void*)&batch_nodes,
        (void*)&inv, (void*)&appear, (void*)&kcount, (void*)&deg,
        (void*)&musum, (void*)&sqsum, (void*)&bitmap,
        (void*)&W1T, (void*)&W2T, (void*)&featB,
        (void*)&edges, (void*)&xw, (void*)&hbase, (void*)&yw, (void*)&out,
        (void*)&syncbuf};

    hipError_t err = hipLaunchCooperativeKernel((const void*)k_mega, dim3(NBLK),
                                                dim3(NTHR), kargs, 0, stream);
    if (err != hipSuccess) {
        // Fallback: original verified 12-kernel pipeline.
        k_wt<<<dim3(16, 16, 2), 256, 0, stream>>>(W1, W2, W1T, W2T);
        k_init<<<(NNODES + 255) / 256, 256, 0, stream>>>(inv, appear, deg, musum, sqsum, kcount);
        k_scatter_inv<<<BATCH / 256, 256, 0, stream>>>(batch_nodes, inv);

        k_mask<<<dim3(512, 1, RNUM), 256, 0, stream>>>(edge_index, inv, appear, edges, kcount);
        k_scan2048<<<RNUM, 1024, 0, stream>>>(appear, rankA);
        k_deg<<<dim3(64, 1, RNUM), 256, 0, stream>>>(edges, rankA, kcount, deg);

        k_gemm1<<<dim3(HID / 64, BATCH / 64, RNUM), 256, 0, stream>>>(
            features, batch_nodes, W1T, b1, deg, xw, hbase);
        k_agg<<<dim3(256, 1, RNUM), 256, 0, stream>>>(edges, kcount, deg, xw, hbase, HID);

        k_bnstats<<<dim3(64, 1, RNUM), 256, 0, stream>>>(hbase, musum, sqsum);
        k_bnfinal<<<RNUM, HID, 0, stream>>>(musum, sqsum, gamma, beta, rstdg, shiftc);

        k_gemm2<<<dim3(OUTC / 64, BATCH / 64, RNUM), 256, 0, stream>>>(
            hbase, rstdg, shiftc, W2T, b2, deg, yw, out);
        k_agg<<<dim3(256, 1, RNUM), 256, 0, stream>>>(edges, kcount, deg, yw, out, OUTC);
    }
}

// Round 3
// 322.571 us; speedup vs baseline: 2.8547x; 2.3558x over previous
//
#include <hip/hip_runtime.h>
#include <hip/hip_bf16.h>
#include <stdint.h>
#include <stddef.h>

#define RNUM   3
#define NNODES 50000
#define ENUM   1000000
#define BATCH  2048
#define INP    256
#define HID    512
#define OUTC   256
#define BN_EPS 1e-5f
#define NBLK   768
#define NTHR   256
#define BMW    1568   // bitmap words: ceil(50000/32)=1563, padded

typedef __bf16 bf16x8 __attribute__((ext_vector_type(8)));
typedef float  f32x4  __attribute__((ext_vector_type(4)));

__device__ inline unsigned short f2bf(float f) {
    union { float f; unsigned u; } c; c.f = f;
    unsigned u = c.u;
    return (unsigned short)((u + 0x7fffu + ((u >> 16) & 1u)) >> 16);  // RNE
}

__device__ inline uint4 pack8(float4 a, float4 b) {
    uint4 r;
    r.x = (unsigned)f2bf(a.x) | ((unsigned)f2bf(a.y) << 16);
    r.y = (unsigned)f2bf(a.z) | ((unsigned)f2bf(a.w) << 16);
    r.z = (unsigned)f2bf(b.x) | ((unsigned)f2bf(b.y) << 16);
    r.w = (unsigned)f2bf(b.z) | ((unsigned)f2bf(b.w) << 16);
    return r;
}

// =====================================================================
// K1: setup — bitmap, inv scatter, zeroing, W^T bf16, featB bf16 gather.
// grid 768 x 256. Roles by blockIdx (verified in mega-kernel phase 0).
// =====================================================================
__global__ __launch_bounds__(256) void k_setup(
    const float* __restrict__ features, const float* __restrict__ W1,
    const float* __restrict__ W2, const int* __restrict__ bn,
    unsigned* __restrict__ bitmap, int* __restrict__ inv,
    int* __restrict__ appear, int* __restrict__ kcount,
    float* __restrict__ musum, float* __restrict__ sqsum,
    float* __restrict__ aggbuf,
    unsigned short* __restrict__ W1T, unsigned short* __restrict__ W2T,
    unsigned short* __restrict__ featB) {
    __shared__ float T[32 * 33];
    const int tid = threadIdx.x;
    const int bid = blockIdx.x;

    // zero aggbuf: RNUM*BATCH*HID floats = 786432 float4 / 768 blocks = 1024/block
    {
        float4* a4 = (float4*)aggbuf;
        int base = bid * 1024;
#pragma unroll
        for (int j = 0; j < 4; ++j)
            a4[base + j * 256 + tid] = make_float4(0.f, 0.f, 0.f, 0.f);
    }

    if (bid == 0) {
        for (int i = tid; i < BMW; i += NTHR) bitmap[i] = 0u;
        __syncthreads();
        for (int i = tid; i < BATCH; i += NTHR) {
            int v = bn[i];
            atomicOr(&bitmap[v >> 5], 1u << (v & 31));
        }
    } else if (bid == 1) {
        for (int i = tid; i < BATCH; i += NTHR) inv[bn[i]] = i;
        for (int i = tid; i < RNUM * BATCH; i += NTHR) appear[i] = 0;
        for (int i = tid; i < RNUM * HID; i += NTHR) { musum[i] = 0.f; sqsum[i] = 0.f; }
        if (tid < RNUM) kcount[tid] = 0;
    }

    if (bid < 256) {
        // weight transpose+bf16: 256 tile jobs (z=0: 8x16 tiles, z=1: 16x8)
        int i = bid;
        int z = i >> 7; i &= 127;
        const float* W = z ? W2 : W1;
        unsigned short* WT = z ? W2T : W1T;
        int K = z ? HID : INP;
        int N = z ? OUTC : HID;
        int kt, nt;
        if (z == 0) { nt = i & 15; kt = i >> 4; } else { nt = i & 7; kt = i >> 3; }
        int tx = tid & 31, ty = tid >> 5;
#pragma unroll
        for (int j = 0; j < 4; ++j)
            T[(ty + j * 8) * 33 + tx] = W[(size_t)(kt * 32 + ty + j * 8) * N + nt * 32 + tx];
        __syncthreads();
#pragma unroll
        for (int j = 0; j < 4; ++j)
            WT[(size_t)(nt * 32 + ty + j * 8) * K + kt * 32 + tx] = f2bf(T[tx * 33 + ty + j * 8]);
    } else if (bid < 640) {
        // featB gather+convert: 384 blocks x 16 rows of [RNUM*BATCH][INP]
        int i = bid - 256;
        int row = i * 16 + (tid >> 4);
        int c0 = (tid & 15) * 16;
        int z = row >> 11, m = row & 2047;
        const float* srow = features + ((size_t)z * NNODES + bn[m]) * INP;
        unsigned short* drow = featB + (size_t)row * INP;
        float4 f0 = *(const float4*)(srow + c0);
        float4 f1 = *(const float4*)(srow + c0 + 4);
        float4 f2 = *(const float4*)(srow + c0 + 8);
        float4 f3 = *(const float4*)(srow + c0 + 12);
        *(uint4*)(drow + c0)     = pack8(f0, f1);
        *(uint4*)(drow + c0 + 8) = pack8(f2, f3);
    }
}

// =====================================================================
// K2: edge mask+compact (bitmap in LDS) THEN gemm1 tile (xw only).
// gemm1 is independent of mask (deg-scaling deferred to k_hbn), so both
// live in one kernel; per block: mask chunk, then its 64x64 GEMM tile.
// grid 768 x 256.
// =====================================================================
__global__ __launch_bounds__(256) void k_maskgemm1(
    const int* __restrict__ edge_index, const unsigned* __restrict__ bitmap,
    const int* __restrict__ inv, int* __restrict__ appear,
    int* __restrict__ kcount, int2* __restrict__ edges,
    const unsigned short* __restrict__ featB,
    const unsigned short* __restrict__ W1T, float* __restrict__ xw) {
    __shared__ __align__(16) unsigned char smem[10240];
    const int tid = threadIdx.x;
    const int bid = blockIdx.x;

    // ---- part A: mask + compact ----
    {
        unsigned* bmL = (unsigned*)smem;   // 6272 B
        for (int i = tid; i < BMW; i += NTHR) bmL[i] = bitmap[i];
        __syncthreads();
        const int gsz = NBLK * NTHR;
        const int g0 = bid * NTHR + tid;
        for (int z = 0; z < RNUM; ++z) {
            const int4* s4 = (const int4*)(edge_index + (size_t)z * 2 * ENUM);
            const int4* d4 = (const int4*)(edge_index + (size_t)z * 2 * ENUM + ENUM);
            int2* ed = edges + (size_t)z * ENUM;
            int* app = appear + z * BATCH;
            for (int i = g0; i < ENUM / 4; i += gsz) {
                int4 S = s4[i], D = d4[i];
                int ss[4] = {S.x, S.y, S.z, S.w};
                int dd[4] = {D.x, D.y, D.z, D.w};
#pragma unroll
                for (int u = 0; u < 4; ++u) {
                    int s = ss[u], d = dd[u];
                    unsigned ks = (bmL[s >> 5] >> (s & 31)) & 1u;
                    unsigned kd = (bmL[d >> 5] >> (d & 31)) & 1u;
                    if (ks & kd) {
                        int ps = inv[s], pd = inv[d];
                        int idx = atomicAdd(&kcount[z], 1);
                        ed[idx] = make_int2(ps, pd);
                        app[ps] = 1;
                        app[pd] = 1;
                    }
                }
            }
        }
        __syncthreads();
    }

    // ---- part B: gemm1 tile -> xw (no deg dependency) ----
    {
        unsigned short* As = (unsigned short*)smem;            // [64][40]
        unsigned short* Bs = (unsigned short*)(smem + 5120);   // [64][40]
        int z = bid >> 8;
        int r = bid & 255;
        int n0 = (r & 7) * 64, m0 = (r >> 3) * 64;
        int ar = tid >> 2, aq = tid & 3;
        const unsigned short* aptr = featB + (size_t)(z * BATCH + m0 + ar) * INP + aq * 8;
        const unsigned short* bptr = W1T + (size_t)(n0 + ar) * INP + aq * 8;
        int lane = tid & 63, wave = tid >> 6;
        int wm = (wave & 1) * 32, wn = (wave >> 1) * 32;
        int ml = lane & 15, quad = lane >> 4, q8 = quad * 8;
        f32x4 acc[2][2] = {};
        for (int k0 = 0; k0 < INP; k0 += 32) {
            uint4 av = *(const uint4*)(aptr + k0);
            uint4 bv = *(const uint4*)(bptr + k0);
            *(uint4*)&As[ar * 40 + aq * 8] = av;
            *(uint4*)&Bs[ar * 40 + aq * 8] = bv;
            __syncthreads();
            bf16x8 af[2], bfr[2];
#pragma unroll
            for (int mi = 0; mi < 2; ++mi) af[mi]  = *(const bf16x8*)&As[(wm + mi * 16 + ml) * 40 + q8];
#pragma unroll
            for (int ni = 0; ni < 2; ++ni) bfr[ni] = *(const bf16x8*)&Bs[(wn + ni * 16 + ml) * 40 + q8];
#pragma unroll
            for (int mi = 0; mi < 2; ++mi)
#pragma unroll
                for (int ni = 0; ni < 2; ++ni)
                    acc[mi][ni] = __builtin_amdgcn_mfma_f32_16x16x32_bf16(af[mi], bfr[ni], acc[mi][ni], 0, 0, 0);
            __syncthreads();
        }
        float* xwz = xw + (size_t)z * BATCH * HID;
#pragma unroll
        for (int mi = 0; mi < 2; ++mi)
#pragma unroll
            for (int rr = 0; rr < 4; ++rr) {
                int row = m0 + wm + mi * 16 + quad * 4 + rr;
#pragma unroll
                for (int ni = 0; ni < 2; ++ni) {
                    int col = n0 + wn + ni * 16 + ml;
                    xwz[(size_t)row * HID + col] = acc[mi][ni][rr];
                }
            }
    }
}

// =====================================================================
// K3: scan(appear) -> rank, remap edges in-place, degree. 3 blocks.
// =====================================================================
__global__ __launch_bounds__(256) void k_scandeg(
    const int* __restrict__ appear, const int* __restrict__ kcount,
    int2* __restrict__ edges, float* __restrict__ deg) {
    __shared__ int rk[BATCH];
    __shared__ float dgf[BATCH];
    __shared__ int wsums[4];
    const int tid = threadIdx.x;
    const int z = blockIdx.x;
    const int* ap = appear + z * BATCH;
    int b0 = tid * 8;
    int pre[8]; int run = 0;
#pragma unroll
    for (int j = 0; j < 8; ++j) { run += ap[b0 + j]; pre[j] = run; }
    int lane = tid & 63, wv = tid >> 6;
    int sc = run;
    for (int off = 1; off < 64; off <<= 1) {
        int n = __shfl_up(sc, off);
        if (lane >= off) sc += n;
    }
    if (lane == 63) wsums[wv] = sc;
    __syncthreads();
    int base = sc - run;
    for (int w = 0; w < wv; ++w) base += wsums[w];
#pragma unroll
    for (int j = 0; j < 8; ++j) { rk[b0 + j] = base + pre[j] - 1; dgf[b0 + j] = 0.f; }
    __syncthreads();
    int K = kcount[z];
    int2* ed = edges + (size_t)z * ENUM;
    for (int e = tid; e < K; e += NTHR) {
        int2 E = ed[e];
        int s = rk[E.x], d = rk[E.y];
        ed[e] = make_int2(s, d);
        atomicAdd(&dgf[d], 1.0f);
    }
    __syncthreads();
    float* dz = deg + z * BATCH;
    for (int i = tid; i < BATCH; i += NTHR) dz[i] = dgf[i];
}

// =====================================================================
// K4/K7: edge aggregation (scatter-add). grid (256,1,RNUM).
// =====================================================================
__global__ void k_agg(const int2* __restrict__ edges, const int* __restrict__ kcount,
                      const float* __restrict__ deg, const float* __restrict__ src_mat,
                      float* __restrict__ dst_mat, int ncol) {
    int z = blockIdx.z;
    int K = kcount[z];
    const int2* ed = edges + (size_t)z * ENUM;
    const float* dgz = deg + z * BATCH;
    const float* sm = src_mat + (size_t)z * BATCH * ncol;
    float* dm = dst_mat + (size_t)z * BATCH * ncol;
    for (int e = blockIdx.x; e < K; e += gridDim.x) {
        int2 E = ed[e];
        float w = rsqrtf(dgz[E.x] + 1.0f) * rsqrtf(dgz[E.y] + 1.0f);
        const float* srow = sm + (size_t)E.x * ncol;
        float* drow = dm + (size_t)E.y * ncol;
        for (int c = threadIdx.x; c < ncol; c += blockDim.x)
            atomicAdd(&drow[c], w * srow[c]);
    }
}

// =====================================================================
// K5: h = d2*xw + b1 + aggbuf  -> hbase, plus BN stats. grid (64,1,RNUM).
// =====================================================================
__global__ __launch_bounds__(256) void k_hbn(
    const float* __restrict__ xw, const float* __restrict__ aggbuf,
    const float* __restrict__ deg, const float* __restrict__ b1,
    float* __restrict__ hbase, float* __restrict__ musum,
    float* __restrict__ sqsum) {
    int z = blockIdx.z;
    const float* xz = xw + (size_t)z * BATCH * HID;
    const float* az = aggbuf + (size_t)z * BATCH * HID;
    float* hz = hbase + (size_t)z * BATCH * HID;
    const float* dgz = deg + z * BATCH;
    int c0 = threadIdx.x;
    int r0 = blockIdx.x * 32;
    float b1a = b1[c0], b1b = b1[c0 + 256];
    float s1a = 0, s2a = 0, s1b = 0, s2b = 0;
    for (int rr = 0; rr < 32; ++rr) {
        int row = r0 + rr;
        float d2 = 1.0f / (dgz[row] + 1.0f);
        size_t off = (size_t)row * HID + c0;
        float ha = xz[off] * d2 + b1a + az[off];
        float hb = xz[off + 256] * d2 + b1b + az[off + 256];
        hz[off] = ha;
        hz[off + 256] = hb;
        s1a += ha; s2a += ha * ha;
        s1b += hb; s2b += hb * hb;
    }
    atomicAdd(&musum[z * HID + c0], s1a);       atomicAdd(&sqsum[z * HID + c0], s2a);
    atomicAdd(&musum[z * HID + c0 + 256], s1b); atomicAdd(&sqsum[z * HID + c0 + 256], s2b);
}

// =====================================================================
// K6: BN-final (prologue) + GEMM2 -> yw, out-base. grid (4,32,RNUM).
// =====================================================================
__global__ __launch_bounds__(256) void k_gemm2f(
    const float* __restrict__ hbase, const float* __restrict__ musum,
    const float* __restrict__ sqsum, const float* __restrict__ gamma,
    const float* __restrict__ beta, const unsigned short* __restrict__ W2T,
    const float* __restrict__ b2, const float* __restrict__ deg,
    float* __restrict__ yw, float* __restrict__ out) {
    __shared__ __align__(16) unsigned short As[64][40];
    __shared__ __align__(16) unsigned short Bs[64][40];
    __shared__ float gL[HID];
    __shared__ float sL[HID];
    int z = blockIdx.z;
    int m0 = blockIdx.y * 64, n0 = blockIdx.x * 64;
    int tid = threadIdx.x;
    for (int c = tid; c < HID; c += NTHR) {
        float mu  = musum[z * HID + c] * (1.0f / BATCH);
        float ex2 = sqsum[z * HID + c] * (1.0f / BATCH);
        float var = ex2 - mu * mu;
        float g = rsqrtf(var + BN_EPS) * gamma[c];
        gL[c] = g;
        sL[c] = beta[c] - mu * g;
    }
    __syncthreads();
    int ar = tid >> 2, aq = tid & 3;
    const float* aptr = hbase + (size_t)z * BATCH * HID + (size_t)(m0 + ar) * HID + aq * 8;
    const unsigned short* bptr = W2T + (size_t)(n0 + ar) * HID + aq * 8;
    int lane = tid & 63, wave = tid >> 6;
    int wm = (wave & 1) * 32, wn = (wave >> 1) * 32;
    int ml = lane & 15, quad = lane >> 4, q8 = quad * 8;
    f32x4 acc[2][2] = {};
    for (int k0 = 0; k0 < HID; k0 += 32) {
        float4 h0 = *(const float4*)(aptr + k0);
        float4 h1 = *(const float4*)(aptr + k0 + 4);
        float4 g0 = *(const float4*)(gL + k0 + aq * 8);
        float4 g1 = *(const float4*)(gL + k0 + aq * 8 + 4);
        float4 s0 = *(const float4*)(sL + k0 + aq * 8);
        float4 s1 = *(const float4*)(sL + k0 + aq * 8 + 4);
        float4 a0 = make_float4(h0.x * g0.x + s0.x, h0.y * g0.y + s0.y,
                                h0.z * g0.z + s0.z, h0.w * g0.w + s0.w);
        float4 a1 = make_float4(h1.x * g1.x + s1.x, h1.y * g1.y + s1.y,
                                h1.z * g1.z + s1.z, h1.w * g1.w + s1.w);
        uint4 bv = *(const uint4*)(bptr + k0);
        *(uint4*)&As[ar][aq * 8] = pack8(a0, a1);
        *(uint4*)&Bs[ar][aq * 8] = bv;
        __syncthreads();
        bf16x8 af[2], bfr[2];
#pragma unroll
        for (int mi = 0; mi < 2; ++mi) af[mi]  = *(const bf16x8*)&As[wm + mi * 16 + ml][q8];
#pragma unroll
        for (int ni = 0; ni < 2; ++ni) bfr[ni] = *(const bf16x8*)&Bs[wn + ni * 16 + ml][q8];
#pragma unroll
        for (int mi = 0; mi < 2; ++mi)
#pragma unroll
            for (int ni = 0; ni < 2; ++ni)
                acc[mi][ni] = __builtin_amdgcn_mfma_f32_16x16x32_bf16(af[mi], bfr[ni], acc[mi][ni], 0, 0, 0);
        __syncthreads();
    }
    const float* dgz = deg + z * BATCH;
    float* ywz = yw + (size_t)z * BATCH * OUTC;
    float* oz = out + (size_t)z * BATCH * OUTC;
#pragma unroll
    for (int mi = 0; mi < 2; ++mi)
#pragma unroll
        for (int rr = 0; rr < 4; ++rr) {
            int row = m0 + wm + mi * 16 + quad * 4 + rr;
            float d2 = 1.0f / (dgz[row] + 1.0f);
#pragma unroll
            for (int ni = 0; ni < 2; ++ni) {
                int col = n0 + wn + ni * 16 + ml;
                float c = acc[mi][ni][rr];
                ywz[(size_t)row * OUTC + col] = c;
                oz[(size_t)row * OUTC + col] = d2 * c + b2[col];
            }
        }
}

// ---------------- launch ----------------
extern "C" void kernel_launch(void* const* d_in, const int* in_sizes, int n_in,
                              void* d_out, int out_size, void* d_ws, size_t ws_size,
                              hipStream_t stream) {
    const float* features    = (const float*)d_in[0];
    const float* W1          = (const float*)d_in[1];
    const float* b1          = (const float*)d_in[2];
    const float* W2          = (const float*)d_in[3];
    const float* b2          = (const float*)d_in[4];
    const float* gamma       = (const float*)d_in[5];
    const float* beta        = (const float*)d_in[6];
    const int*   edge_index  = (const int*)d_in[7];
    const int*   batch_nodes = (const int*)d_in[8];
    float* out = (float*)d_out;

    char* p = (char*)d_ws;
    size_t cur = 0;
    auto alloc = [&](size_t bytes) {
        void* r = p + cur;
        cur = (cur + bytes + 255) & ~(size_t)255;
        return r;
    };
    int*   inv    = (int*)  alloc(NNODES * sizeof(int));
    int*   appear = (int*)  alloc(RNUM * BATCH * sizeof(int));
    int*   kcount = (int*)  alloc(RNUM * sizeof(int));
    float* deg    = (float*)alloc(RNUM * BATCH * sizeof(float));
    float* musum  = (float*)alloc(RNUM * HID * sizeof(float));
    float* sqsum  = (float*)alloc(RNUM * HID * sizeof(float));
    unsigned* bitmap = (unsigned*)alloc(BMW * sizeof(unsigned));
    unsigned short* W1T = (unsigned short*)alloc((size_t)HID * INP * sizeof(unsigned short));
    unsigned short* W2T = (unsigned short*)alloc((size_t)OUTC * HID * sizeof(unsigned short));
    unsigned short* featB = (unsigned short*)alloc((size_t)RNUM * BATCH * INP * sizeof(unsigned short));
    int2*  edges  = (int2*) alloc((size_t)RNUM * ENUM * sizeof(int2));
    float* xw     = (float*)alloc((size_t)RNUM * BATCH * HID * sizeof(float));
    float* aggbuf = (float*)alloc((size_t)RNUM * BATCH * HID * sizeof(float));
    float* hbase  = (float*)alloc((size_t)RNUM * BATCH * HID * sizeof(float));
    float* yw     = (float*)alloc((size_t)RNUM * BATCH * OUTC * sizeof(float));
    (void)ws_size; (void)in_sizes; (void)n_in; (void)out_size;

    k_setup<<<NBLK, NTHR, 0, stream>>>(features, W1, W2, batch_nodes,
                                       bitmap, inv, appear, kcount,
                                       musum, sqsum, aggbuf, W1T, W2T, featB);

    k_maskgemm1<<<NBLK, NTHR, 0, stream>>>(edge_index, bitmap, inv, appear,
                                           kcount, edges, featB, W1T, xw);

    k_scandeg<<<RNUM, NTHR, 0, stream>>>(appear, kcount, edges, deg);

    k_agg<<<dim3(256, 1, RNUM), NTHR, 0, stream>>>(edges, kcount, deg, xw, aggbuf, HID);

    k_hbn<<<dim3(64, 1, RNUM), NTHR, 0, stream>>>(xw, aggbuf, deg, b1,
                                                  hbase, musum, sqsum);

    k_gemm2f<<<dim3(OUTC / 64, BATCH / 64, RNUM), NTHR, 0, stream>>>(
        hbase, musum, sqsum, gamma, beta, W2T, b2, deg, yw, out);

    k_agg<<<dim3(256, 1, RNUM), NTHR, 0, stream>>>(edges, kcount, deg, yw, out, OUTC);
}